// Round 1
// baseline (1383.112 us; speedup 1.0000x reference)
//
#include <hip/hip_runtime.h>
#include <math.h>
#include <float.h>

#define HN 256
#define DN 512
#define CCLS 1000
#define BB 16
#define SS 1024
#define NSTEPS 8
#define G4 1024   // 4*H

// ---------------- v_norm = g / ||v_mono|| ----------------
__global__ __launch_bounds__(512) void vnorm_k(const float* __restrict__ v,
                                               const float* __restrict__ g,
                                               float* __restrict__ out) {
    __shared__ float red[512];
    int t = threadIdx.x;
    float x = v[t];
    red[t] = x * x;
    __syncthreads();
    for (int off = 256; off > 0; off >>= 1) {
        if (t < off) red[t] += red[t + off];
        __syncthreads();
    }
    if (t == 0) out[0] = g[0] / sqrtf(red[0]);
}

// ---------------- dual GEMM: C1 = A@W1, C2 = A@W2 ----------------
// A: [M=16384, K=512] row-major; W: [K=512, N=512]; C: [M, N]
#define BM 64
#define BN 64
#define BKK 16
__global__ __launch_bounds__(256) void gemm_dual(const float* __restrict__ A,
                                                 const float* __restrict__ W1,
                                                 const float* __restrict__ W2,
                                                 float* __restrict__ C1,
                                                 float* __restrict__ C2) {
    const int M = BB * SS, N = DN, K = DN;
    (void)M;
    __shared__ float As[BKK][BM];
    __shared__ float B1s[BKK][BN];
    __shared__ float B2s[BKK][BN];
    int bm = blockIdx.x;   // 256
    int bn = blockIdx.y;   // 8
    int tid = threadIdx.x;
    int tx = tid % 16, ty = tid / 16;
    float acc1[4][4] = {{0}}, acc2[4][4] = {{0}};
    int rowA = tid / 4;          // 0..63
    int colA = (tid % 4) * 4;    // 0,4,8,12
    int rowW = tid / 16;         // 0..15
    int colW = (tid % 16) * 4;   // 0..60
    const float* Ab = A + (size_t)(bm * BM) * K;
    for (int k0 = 0; k0 < K; k0 += BKK) {
        float4 a4 = *(const float4*)(Ab + (size_t)rowA * K + k0 + colA);
        As[colA + 0][rowA] = a4.x;
        As[colA + 1][rowA] = a4.y;
        As[colA + 2][rowA] = a4.z;
        As[colA + 3][rowA] = a4.w;
        *(float4*)&B1s[rowW][colW] = *(const float4*)(W1 + (size_t)(k0 + rowW) * N + bn * BN + colW);
        *(float4*)&B2s[rowW][colW] = *(const float4*)(W2 + (size_t)(k0 + rowW) * N + bn * BN + colW);
        __syncthreads();
#pragma unroll
        for (int k = 0; k < BKK; ++k) {
            float a[4], b1[4], b2[4];
#pragma unroll
            for (int i = 0; i < 4; i++) a[i] = As[k][ty * 4 + i];
#pragma unroll
            for (int j = 0; j < 4; j++) b1[j] = B1s[k][tx * 4 + j];
#pragma unroll
            for (int j = 0; j < 4; j++) b2[j] = B2s[k][tx * 4 + j];
#pragma unroll
            for (int i = 0; i < 4; i++)
#pragma unroll
                for (int j = 0; j < 4; j++) {
                    acc1[i][j] = fmaf(a[i], b1[j], acc1[i][j]);
                    acc2[i][j] = fmaf(a[i], b2[j], acc2[i][j]);
                }
        }
        __syncthreads();
    }
    for (int i = 0; i < 4; i++) {
        int r = bm * BM + ty * 4 + i;
        for (int j = 0; j < 4; j++) {
            int cidx = bn * BN + tx * 4 + j;
            C1[(size_t)r * N + cidx] = acc1[i][j];
            C2[(size_t)r * N + cidx] = acc2[i][j];
        }
    }
}

// ---------------- a0 init ----------------
__global__ void inita_k(float* __restrict__ a) {
    int b = threadIdx.x;
    if (b < BB) a[(size_t)b * SS] = 1.f;
}

// ---------------- sm = s@Ws_mono + b ; sc = s@Ws_chunk + b ----------------
__global__ __launch_bounds__(512) void proj_k(const float* __restrict__ s,
                                              const float* __restrict__ Wm, const float* __restrict__ bm,
                                              const float* __restrict__ Wc, const float* __restrict__ bc,
                                              float* __restrict__ sm, float* __restrict__ sc) {
    int b = blockIdx.x;
    int d = threadIdx.x;
    __shared__ float sl[HN];
    if (d < HN) sl[d] = s[b * HN + d];
    __syncthreads();
    float a1 = bm[d], a2 = bc[d];
    for (int k = 0; k < HN; k++) {
        float sv = sl[k];
        a1 = fmaf(sv, Wm[(size_t)k * DN + d], a1);
        a2 = fmaf(sv, Wc[(size_t)k * DN + d], a2);
    }
    sm[b * DN + d] = a1;
    sc[b * DN + d] = a2;
}

// ---------------- energies: one wave per (b,s) row ----------------
__global__ __launch_bounds__(256) void energy_k(const float* __restrict__ encM,
                                                const float* __restrict__ encC,
                                                const float* __restrict__ sm, const float* __restrict__ sc,
                                                const float* __restrict__ vM, const float* __restrict__ vC,
                                                const float* __restrict__ vnorm, const float* __restrict__ rmono,
                                                const int* __restrict__ len, const float* __restrict__ noise_t,
                                                float* __restrict__ p, float* __restrict__ ech) {
    int wave = blockIdx.x * 4 + (threadIdx.x >> 6);
    int lane = threadIdx.x & 63;
    int b = wave >> 10;
    int si = wave & 1023;
    const float* em = encM + (size_t)wave * DN;
    const float* ec = encC + (size_t)wave * DN;
    const float* smb = sm + b * DN;
    const float* scb = sc + b * DN;
    float s1 = 0.f, s2 = 0.f;
#pragma unroll
    for (int j = 0; j < 8; j++) {
        int d = lane + j * 64;
        s1 += tanhf(em[d] + smb[d]) * vM[d];
        s2 += tanhf(ec[d] + scb[d]) * vC[d];
    }
#pragma unroll
    for (int off = 32; off > 0; off >>= 1) {
        s1 += __shfl_xor(s1, off);
        s2 += __shfl_xor(s2, off);
    }
    if (lane == 0) {
        bool masked = (si >= len[b]);
        float pe;
        if (masked) {
            pe = 0.f;
        } else {
            float e = vnorm[0] * s1 + rmono[0] + noise_t[b * SS + si];
            pe = 1.f / (1.f + expf(-e));
        }
        p[b * SS + si] = pe;
        ech[b * SS + si] = masked ? -INFINITY : s2;
    }
}

// ---------------- per-row scan: alpha recurrence + chunk softmax + beta ----------------
__global__ __launch_bounds__(1024) void scanrow_k(const float* __restrict__ p,
                                                  const float* __restrict__ aprev,
                                                  const float* __restrict__ ech,
                                                  float* __restrict__ anew,
                                                  float* __restrict__ beta) {
    int b = blockIdx.x;
    int i = threadIdx.x;
    __shared__ float sc[SS];
    __shared__ float exS[SS];
    __shared__ float rS[SS];
    float pi = p[b * SS + i];
    // --- scan 1: cumsum of log(clip(1-p,1e-8,1)) over indices 0..S-2 ---
    float lf = (i < SS - 1) ? logf(fminf(fmaxf(1.f - pi, 1e-8f), 1.f)) : 0.f;
    sc[i] = lf;
    __syncthreads();
    for (int off = 1; off < SS; off <<= 1) {
        float add = (i >= off) ? sc[i - off] : 0.f;
        __syncthreads();
        sc[i] += add;
        __syncthreads();
    }
    float cpp = (i == 0) ? 1.f : expf(sc[i - 1]);
    // --- scan 2: cumsum of a_prev / clip(cpp,1e-8,1) ---
    float u = aprev[b * SS + i] / fminf(fmaxf(cpp, 1e-8f), 1.f);
    __syncthreads();          // all cpp reads of sc done before overwrite
    sc[i] = u;
    __syncthreads();
    for (int off = 1; off < SS; off <<= 1) {
        float add = (i >= off) ? sc[i - off] : 0.f;
        __syncthreads();
        sc[i] += add;
        __syncthreads();
    }
    float q = cpp * sc[i];
    float alpha = fminf(fmaxf(pi * q, 1e-8f), 1.f);
    anew[b * SS + i] = alpha;
    // --- chunk softmax pieces ---
    float e = ech[b * SS + i];
    sc[i] = e;
    for (int off = 512; off > 0; off >>= 1) {
        __syncthreads();
        if (i < off) sc[i] = fmaxf(sc[i], sc[i + off]);
    }
    __syncthreads();
    float m = sc[0];
    float ex = expf(e - m);
    ex = fmaxf(ex, 1e-5f);     // clip(exp, 1e-5, None); exp(e-m) <= 1
    exS[i] = ex;
    __syncthreads();
    float denom = ex;
    if (i >= 1) denom += exS[i - 1];
    if (i >= 2) denom += exS[i - 2];
    if (i >= 3) denom += exS[i - 3];
    denom = fmaxf(denom, 1e-10f);
    rS[i] = alpha / denom;
    __syncthreads();
    float bsum = rS[i];
    if (i + 1 < SS) bsum += rS[i + 1];
    if (i + 2 < SS) bsum += rS[i + 2];
    if (i + 3 < SS) bsum += rS[i + 3];
    beta[b * SS + i] = ex * bsum;
}

// ---------------- ctx partial: [b, schunk] blocks, 512 threads (one d each) ----------------
__global__ __launch_bounds__(512) void ctxpart_k(const float* __restrict__ beta,
                                                 const float* __restrict__ enc,
                                                 float* __restrict__ part) {
    int b = blockIdx.x, scN = blockIdx.y;
    int d = threadIdx.x;
    int s0 = scN * 64;
    float acc = 0.f;
    const float* eb = enc + ((size_t)b * SS + s0) * DN + d;
    const float* bb_ = beta + b * SS + s0;
    for (int s = 0; s < 64; s++) acc = fmaf(bb_[s], eb[(size_t)s * DN], acc);
    part[((size_t)b * 16 + scN) * DN + d] = acc;
}

__global__ __launch_bounds__(512) void ctxred_k(const float* __restrict__ part,
                                                float* __restrict__ ctx) {
    int b = blockIdx.x;
    int d = threadIdx.x;
    float acc = 0.f;
    for (int j = 0; j < 16; j++) acc += part[((size_t)b * 16 + j) * DN + d];
    ctx[b * DN + d] = acc;
}

// ---------------- LSTM cell (updates s, c in place) ----------------
__global__ __launch_bounds__(256) void lstm_k(const int* __restrict__ target, int t,
                                              const float* __restrict__ Lys, const float* __restrict__ Lss,
                                              const float* __restrict__ Lgs, const float* __restrict__ Lgsb,
                                              const float* __restrict__ ctx,
                                              float* __restrict__ s, float* __restrict__ c) {
    int b = blockIdx.x;
    int h = threadIdx.x;
    __shared__ float sl[HN];
    __shared__ float cl[DN];
    sl[h] = s[b * HN + h];
    cl[h] = ctx[b * DN + h];
    cl[h + HN] = ctx[b * DN + HN + h];
    __syncthreads();
    int tgt = target[b * NSTEPS + t];
    const float* ys = Lys + (size_t)tgt * G4;
    float ri = ys[h] + Lgsb[h];
    float rf = ys[h + HN] + Lgsb[h + HN];
    float rg = ys[h + 2 * HN] + Lgsb[h + 2 * HN];
    float ro = ys[h + 3 * HN] + Lgsb[h + 3 * HN];
    for (int k = 0; k < HN; k++) {
        float sv = sl[k];
        const float* row = Lss + (size_t)k * G4;
        ri = fmaf(sv, row[h], ri);
        rf = fmaf(sv, row[h + HN], rf);
        rg = fmaf(sv, row[h + 2 * HN], rg);
        ro = fmaf(sv, row[h + 3 * HN], ro);
    }
    for (int k = 0; k < DN; k++) {
        float cv = cl[k];
        const float* row = Lgs + (size_t)k * G4;
        ri = fmaf(cv, row[h], ri);
        rf = fmaf(cv, row[h + HN], rf);
        rg = fmaf(cv, row[h + 2 * HN], rg);
        ro = fmaf(cv, row[h + 3 * HN], ro);
    }
    float sig_i = 1.f / (1.f + expf(-ri));
    float sig_f = 1.f / (1.f + expf(-rf));
    float sig_o = 1.f / (1.f + expf(-ro));
    float cn = sig_f * c[b * HN + h] + sig_i * tanhf(rg);
    float sn = sig_o * tanhf(cn);
    c[b * HN + h] = cn;
    s[b * HN + h] = sn;
}

// ---------------- output projection ----------------
__global__ __launch_bounds__(256) void out_k(const float* __restrict__ ctx, const float* __restrict__ s,
                                             const float* __restrict__ Lgy, const float* __restrict__ Lgyb,
                                             const float* __restrict__ Lsy,
                                             const float* __restrict__ Lyy, const float* __restrict__ Lyyb,
                                             float* __restrict__ out, int t) {
    int b = blockIdx.x;
    int h = threadIdx.x;
    __shared__ float cl[DN];
    __shared__ float sl[HN];
    __shared__ float yv[HN];
    cl[h] = ctx[b * DN + h];
    cl[h + HN] = ctx[b * DN + HN + h];
    sl[h] = s[b * HN + h];
    __syncthreads();
    float acc = Lgyb[h];
    for (int d = 0; d < DN; d++) acc = fmaf(cl[d], Lgy[(size_t)d * HN + h], acc);
    for (int k = 0; k < HN; k++) acc = fmaf(sl[k], Lsy[(size_t)k * HN + h], acc);
    yv[h] = tanhf(acc);
    __syncthreads();
    float* ob = out + ((size_t)b * NSTEPS + t) * CCLS;
    for (int cc = h; cc < CCLS; cc += HN) {
        float a2 = Lyyb[cc];
        for (int k = 0; k < HN; k++) a2 = fmaf(yv[k], Lyy[(size_t)k * CCLS + cc], a2);
        ob[cc] = a2;
    }
}

extern "C" void kernel_launch(void* const* d_in, const int* in_sizes, int n_in,
                              void* d_out, int out_size, void* d_ws, size_t ws_size,
                              hipStream_t stream) {
    const float* enc  = (const float*)d_in[0];
    const int*   target = (const int*)d_in[1];
    const int*   len  = (const int*)d_in[2];
    const float* noise = (const float*)d_in[3];
    const float* Wsm  = (const float*)d_in[4];
    const float* Wsmb = (const float*)d_in[5];
    const float* WhM  = (const float*)d_in[6];
    const float* vM   = (const float*)d_in[7];
    const float* g    = (const float*)d_in[8];
    const float* rm   = (const float*)d_in[9];
    const float* Wsc  = (const float*)d_in[10];
    const float* Wscb = (const float*)d_in[11];
    const float* WhC  = (const float*)d_in[12];
    const float* vC   = (const float*)d_in[13];
    const float* Lsy  = (const float*)d_in[14];
    const float* Lgy  = (const float*)d_in[15];
    const float* Lgyb = (const float*)d_in[16];
    const float* Lyy  = (const float*)d_in[17];
    const float* Lyyb = (const float*)d_in[18];
    const float* Lys  = (const float*)d_in[19];
    const float* Lss  = (const float*)d_in[20];
    const float* Lgs  = (const float*)d_in[21];
    const float* Lgsb = (const float*)d_in[22];
    float* out = (float*)d_out;

    float* w = (float*)d_ws;
    size_t off = 0;
    auto alloc = [&](size_t n) { float* pp = w + off; off += n; return pp; };
    float* encM  = alloc((size_t)BB * SS * DN);
    float* encC  = alloc((size_t)BB * SS * DN);
    float* smb   = alloc(BB * DN);
    float* scb   = alloc(BB * DN);
    float* pbuf  = alloc(BB * SS);
    float* ech   = alloc(BB * SS);
    float* aA    = alloc(BB * SS);
    float* aBf   = alloc(BB * SS);
    float* betab = alloc(BB * SS);
    float* part  = alloc((size_t)BB * 16 * DN);
    float* ctx   = alloc(BB * DN);
    float* sbuf  = alloc(BB * HN);
    float* cbuf  = alloc(BB * HN);
    float* vn    = alloc(1);
    (void)ws_size; (void)in_sizes; (void)n_in; (void)out_size;

    vnorm_k<<<1, 512, 0, stream>>>(vM, g, vn);
    gemm_dual<<<dim3(BB * SS / BM, DN / BN), 256, 0, stream>>>(enc, WhM, WhC, encM, encC);
    hipMemsetAsync(sbuf, 0, BB * HN * sizeof(float), stream);
    hipMemsetAsync(cbuf, 0, BB * HN * sizeof(float), stream);
    hipMemsetAsync(aA, 0, BB * SS * sizeof(float), stream);
    inita_k<<<1, 64, 0, stream>>>(aA);

    for (int t = 0; t < NSTEPS; t++) {
        float* ain  = (t % 2 == 0) ? aA : aBf;
        float* aout = (t % 2 == 0) ? aBf : aA;
        proj_k<<<BB, 512, 0, stream>>>(sbuf, Wsm, Wsmb, Wsc, Wscb, smb, scb);
        energy_k<<<BB * SS / 4, 256, 0, stream>>>(encM, encC, smb, scb, vM, vC, vn, rm,
                                                  len, noise + (size_t)t * BB * SS, pbuf, ech);
        scanrow_k<<<BB, 1024, 0, stream>>>(pbuf, ain, ech, aout, betab);
        ctxpart_k<<<dim3(BB, 16), 512, 0, stream>>>(betab, enc, part);
        ctxred_k<<<BB, 512, 0, stream>>>(part, ctx);
        lstm_k<<<BB, 256, 0, stream>>>(target, t, Lys, Lss, Lgs, Lgsb, ctx, sbuf, cbuf);
        out_k<<<BB, 256, 0, stream>>>(ctx, sbuf, Lgy, Lgyb, Lsy, Lyy, Lyyb, out, t);
    }
}

// Round 2
// 1132.729 us; speedup vs baseline: 1.2210x; 1.2210x over previous
//
#include <hip/hip_runtime.h>
#include <math.h>
#include <float.h>

#define HN 256
#define DN 512
#define CCLS 1000
#define BB 16
#define SS 1024
#define NSTEPS 8
#define G4 1024   // 4*H

using f16x8 = __attribute__((ext_vector_type(8))) _Float16;
using f32x4 = __attribute__((ext_vector_type(4))) float;

__device__ __forceinline__ void gload_lds16(const void* g, void* l) {
    __builtin_amdgcn_global_load_lds((const __attribute__((address_space(1))) void*)g,
                                     (__attribute__((address_space(3))) void*)l, 16, 0, 0);
}

// ---------------- v_norm = g / ||v_mono|| ----------------
__global__ __launch_bounds__(512) void vnorm_k(const float* __restrict__ v,
                                               const float* __restrict__ g,
                                               float* __restrict__ out) {
    __shared__ float red[512];
    int t = threadIdx.x;
    float x = v[t];
    red[t] = x * x;
    __syncthreads();
    for (int off = 256; off > 0; off >>= 1) {
        if (t < off) red[t] += red[t + off];
        __syncthreads();
    }
    if (t == 0) out[0] = g[0] / sqrtf(red[0]);
}

// ---------------- f32 -> f16 conversion of enc ----------------
__global__ __launch_bounds__(256) void conv_enc_k(const float* __restrict__ in,
                                                  _Float16* __restrict__ out) {
    size_t i = ((size_t)blockIdx.x * 256 + threadIdx.x) * 8;
    float4 a = *(const float4*)(in + i);
    float4 b = *(const float4*)(in + i + 4);
    f16x8 o;
    o[0] = (_Float16)a.x; o[1] = (_Float16)a.y; o[2] = (_Float16)a.z; o[3] = (_Float16)a.w;
    o[4] = (_Float16)b.x; o[5] = (_Float16)b.y; o[6] = (_Float16)b.z; o[7] = (_Float16)b.w;
    *(f16x8*)(out + i) = o;
}

// ---------------- build WcT [1024][512] f16 = transpose of [W1 | W2] ----------------
__global__ __launch_bounds__(256) void convW_k(const float* __restrict__ W1,
                                               const float* __restrict__ W2,
                                               _Float16* __restrict__ WcT) {
    int kt = blockIdx.x;   // 16 tiles over K=512
    int nt = blockIdx.y;   // 32 tiles over N=1024
    __shared__ _Float16 tile[32][33];
    int tx = threadIdx.x & 31, ty = threadIdx.x >> 5;   // ty 0..7
    int n0 = nt * 32, k0 = kt * 32;
    for (int r = 0; r < 32; r += 8) {
        int k = k0 + ty + r, n = n0 + tx;
        float v = (n < 512) ? W1[(size_t)k * 512 + n] : W2[(size_t)k * 512 + (n - 512)];
        tile[tx][ty + r] = (_Float16)v;
    }
    __syncthreads();
    for (int r = 0; r < 32; r += 8) {
        int n = n0 + ty + r, k = k0 + tx;
        WcT[(size_t)n * 512 + k] = tile[ty + r][tx];
    }
}

// ---------------- f16 MFMA GEMM: encMC[M=16384][1024] = A16 @ WcT^T ----------------
// A16 [16384][512] f16 row-major; WcT [1024][512] f16 (N-major, K contiguous)
__global__ __launch_bounds__(256) void gemm16_k(const _Float16* __restrict__ A16,
                                                const _Float16* __restrict__ WcT,
                                                _Float16* __restrict__ encMC) {
    __shared__ _Float16 Alds[128 * 32];
    __shared__ _Float16 Blds[128 * 32];
    int bm = blockIdx.x;   // 128
    int bn = blockIdx.y;   // 8
    int tid = threadIdx.x;
    int lane = tid & 63;
    int w = tid >> 6;          // 4 waves
    int wr = w >> 1, wc = w & 1;   // wave -> 64x64 quadrant
    int lr = lane & 15;
    int kg = lane >> 4;        // 0..3
    f32x4 acc[4][4];
#pragma unroll
    for (int i = 0; i < 4; i++)
#pragma unroll
        for (int j = 0; j < 4; j++) acc[i][j] = (f32x4){0.f, 0.f, 0.f, 0.f};

    int wavebase = tid & ~63;
    for (int k0 = 0; k0 < 512; k0 += 32) {
        __syncthreads();
#pragma unroll
        for (int is = 0; is < 2; is++) {
            int l = is * 256 + tid;
            int row = l >> 2, kgs = l & 3;
            int kp = kgs ^ ((row ^ (row >> 2)) & 3);
            gload_lds16(A16 + (size_t)(bm * 128 + row) * 512 + k0 + kp * 8,
                        (char*)Alds + (size_t)(is * 256 + wavebase) * 16);
            gload_lds16(WcT + (size_t)(bn * 128 + row) * 512 + k0 + kp * 8,
                        (char*)Blds + (size_t)(is * 256 + wavebase) * 16);
        }
        __syncthreads();
        f16x8 af[4], bf[4];
#pragma unroll
        for (int mi = 0; mi < 4; mi++) {
            int r = wr * 64 + mi * 16 + lr;
            int kp = kg ^ ((r ^ (r >> 2)) & 3);
            af[mi] = *(const f16x8*)(Alds + r * 32 + kp * 8);
        }
#pragma unroll
        for (int ni = 0; ni < 4; ni++) {
            int cgl = wc * 64 + ni * 16 + lr;
            int kp = kg ^ ((cgl ^ (cgl >> 2)) & 3);
            bf[ni] = *(const f16x8*)(Blds + cgl * 32 + kp * 8);
        }
#pragma unroll
        for (int mi = 0; mi < 4; mi++)
#pragma unroll
            for (int ni = 0; ni < 4; ni++)
                acc[mi][ni] = __builtin_amdgcn_mfma_f32_16x16x32_f16(af[mi], bf[ni], acc[mi][ni], 0, 0, 0);
    }
    int cr = lane >> 4;
#pragma unroll
    for (int mi = 0; mi < 4; mi++)
#pragma unroll
        for (int ni = 0; ni < 4; ni++) {
            int col = bn * 128 + wc * 64 + ni * 16 + lr;
#pragma unroll
            for (int j = 0; j < 4; j++) {
                int row = bm * 128 + wr * 64 + mi * 16 + cr * 4 + j;
                encMC[(size_t)row * 1024 + col] = (_Float16)acc[mi][ni][j];
            }
        }
}

// ---------------- a0 init ----------------
__global__ void inita_k(float* __restrict__ a) {
    int b = threadIdx.x;
    if (b < BB) a[(size_t)b * SS] = 1.f;
}

// ---------------- initial sm/sc (s=0) ----------------
__global__ __launch_bounds__(512) void proj_k(const float* __restrict__ s,
                                              const float* __restrict__ Wm, const float* __restrict__ bm,
                                              const float* __restrict__ Wc, const float* __restrict__ bc,
                                              float* __restrict__ sm, float* __restrict__ sc) {
    int b = blockIdx.x;
    int d = threadIdx.x;
    __shared__ float sl[HN];
    if (d < HN) sl[d] = s[b * HN + d];
    __syncthreads();
    float a1 = bm[d], a2 = bc[d];
    for (int k = 0; k < HN; k++) {
        float sv = sl[k];
        a1 = fmaf(sv, Wm[(size_t)k * DN + d], a1);
        a2 = fmaf(sv, Wc[(size_t)k * DN + d], a2);
    }
    sm[b * DN + d] = a1;
    sc[b * DN + d] = a2;
}

// ---------------- energies: one wave per (b,s) row ----------------
__global__ __launch_bounds__(256) void energy_k(const _Float16* __restrict__ encMC,
                                                const float* __restrict__ sm, const float* __restrict__ sc,
                                                const float* __restrict__ vM, const float* __restrict__ vC,
                                                const float* __restrict__ vnorm, const float* __restrict__ rmono,
                                                const int* __restrict__ len, const float* __restrict__ noise_t,
                                                float* __restrict__ p, float* __restrict__ ech) {
    int wave = blockIdx.x * 4 + (threadIdx.x >> 6);
    int lane = threadIdx.x & 63;
    int b = wave >> 10;
    int si = wave & 1023;
    const f16x8* row = (const f16x8*)(encMC + (size_t)wave * 1024);
    f16x8 em = row[lane];
    f16x8 ec = row[64 + lane];
    int d0 = lane * 8;
    float4 sma = *(const float4*)&sm[b * DN + d0];
    float4 smbv = *(const float4*)&sm[b * DN + d0 + 4];
    float4 sca = *(const float4*)&sc[b * DN + d0];
    float4 scbv = *(const float4*)&sc[b * DN + d0 + 4];
    float4 vma = *(const float4*)&vM[d0];
    float4 vmb = *(const float4*)&vM[d0 + 4];
    float4 vca = *(const float4*)&vC[d0];
    float4 vcb = *(const float4*)&vC[d0 + 4];
    float smv[8] = {sma.x, sma.y, sma.z, sma.w, smbv.x, smbv.y, smbv.z, smbv.w};
    float scv[8] = {sca.x, sca.y, sca.z, sca.w, scbv.x, scbv.y, scbv.z, scbv.w};
    float vmv[8] = {vma.x, vma.y, vma.z, vma.w, vmb.x, vmb.y, vmb.z, vmb.w};
    float vcv[8] = {vca.x, vca.y, vca.z, vca.w, vcb.x, vcb.y, vcb.z, vcb.w};
    float s1 = 0.f, s2 = 0.f;
#pragma unroll
    for (int j = 0; j < 8; j++) {
        s1 += tanhf((float)em[j] + smv[j]) * vmv[j];
        s2 += tanhf((float)ec[j] + scv[j]) * vcv[j];
    }
#pragma unroll
    for (int off = 32; off > 0; off >>= 1) {
        s1 += __shfl_xor(s1, off);
        s2 += __shfl_xor(s2, off);
    }
    if (lane == 0) {
        bool masked = (si >= len[b]);
        float pe;
        if (masked) {
            pe = 0.f;
        } else {
            float e = vnorm[0] * s1 + rmono[0] + noise_t[b * SS + si];
            pe = 1.f / (1.f + expf(-e));
        }
        p[b * SS + si] = pe;
        ech[b * SS + si] = masked ? -INFINITY : s2;
    }
}

// ---------------- per-row scan: alpha recurrence + chunk softmax + beta ----------------
__global__ __launch_bounds__(1024) void scanrow_k(const float* __restrict__ p,
                                                  const float* __restrict__ aprev,
                                                  const float* __restrict__ ech,
                                                  float* __restrict__ anew,
                                                  float* __restrict__ beta) {
    int b = blockIdx.x;
    int i = threadIdx.x;
    int lane = i & 63, w = i >> 6;
    __shared__ float wred[16];
    __shared__ float wred2[16];
    __shared__ float mred[16];
    __shared__ float exS[SS];
    __shared__ float rS[SS];
    float pi = p[b * SS + i];
    float lf = (i < SS - 1) ? logf(fminf(fmaxf(1.f - pi, 1e-8f), 1.f)) : 0.f;
    // wave-level inclusive scan of lf
    float x = lf;
#pragma unroll
    for (int off = 1; off < 64; off <<= 1) {
        float n = __shfl_up(x, off);
        if (lane >= off) x += n;
    }
    if (lane == 63) wred[w] = x;
    // max-reduce of ech (do wave part before barrier)
    float e = ech[b * SS + i];
    float mx = e;
#pragma unroll
    for (int off = 32; off > 0; off >>= 1) mx = fmaxf(mx, __shfl_xor(mx, off));
    if (lane == 0) mred[w] = mx;
    __syncthreads();
    float base = 0.f;
    for (int j = 0; j < 16; j++)
        if (j < w) base += wred[j];
    float csum = base + x;
    float cpp = expf(csum - lf);   // == exp(cumsum through i-1); i==0 -> exp(0)=1
    float u = aprev[b * SS + i] / fminf(fmaxf(cpp, 1e-8f), 1.f);
    float m = mred[0];
    for (int j = 1; j < 16; j++) m = fmaxf(m, mred[j]);
    // wave-level inclusive scan of u
    float x2 = u;
#pragma unroll
    for (int off = 1; off < 64; off <<= 1) {
        float n = __shfl_up(x2, off);
        if (lane >= off) x2 += n;
    }
    if (lane == 63) wred2[w] = x2;
    __syncthreads();
    float base2 = 0.f;
    for (int j = 0; j < 16; j++)
        if (j < w) base2 += wred2[j];
    float q = cpp * (base2 + x2);
    float alpha = fminf(fmaxf(pi * q, 1e-8f), 1.f);
    anew[b * SS + i] = alpha;
    float ex = fmaxf(expf(e - m), 1e-5f);
    exS[i] = ex;
    __syncthreads();
    float denom = ex;
    if (i >= 1) denom += exS[i - 1];
    if (i >= 2) denom += exS[i - 2];
    if (i >= 3) denom += exS[i - 3];
    denom = fmaxf(denom, 1e-10f);
    rS[i] = alpha / denom;
    __syncthreads();
    float bsum = rS[i];
    if (i + 1 < SS) bsum += rS[i + 1];
    if (i + 2 < SS) bsum += rS[i + 2];
    if (i + 3 < SS) bsum += rS[i + 3];
    beta[b * SS + i] = ex * bsum;
}

// ---------------- ctx partial over f16 enc copy ----------------
__global__ __launch_bounds__(512) void ctxpart_k(const float* __restrict__ beta,
                                                 const _Float16* __restrict__ enc16,
                                                 float* __restrict__ part) {
    int b = blockIdx.x, scN = blockIdx.y;
    int d = threadIdx.x;
    int s0 = scN * 64;
    float acc = 0.f;
    const _Float16* eb = enc16 + ((size_t)(b * SS + s0)) * DN + d;
    const float* bb_ = beta + b * SS + s0;
#pragma unroll 4
    for (int s = 0; s < 64; s++) acc = fmaf(bb_[s], (float)eb[(size_t)s * DN], acc);
    part[((size_t)b * 16 + scN) * DN + d] = acc;
}

// ---------------- fused tail: ctx reduce + LSTM + y gate + output + next-step proj ----------------
__global__ __launch_bounds__(256) void tail_k(const float* __restrict__ part,
                                              const int* __restrict__ target, int t,
                                              const float* __restrict__ Lys, const float* __restrict__ Lss,
                                              const float* __restrict__ Lgs, const float* __restrict__ Lgsb,
                                              const float* __restrict__ Lgy, const float* __restrict__ Lgyb,
                                              const float* __restrict__ Lsy,
                                              const float* __restrict__ Lyy, const float* __restrict__ Lyyb,
                                              const float* __restrict__ Wsm, const float* __restrict__ Wsmb,
                                              const float* __restrict__ Wsc, const float* __restrict__ Wscb,
                                              float* __restrict__ s, float* __restrict__ c,
                                              float* __restrict__ smb, float* __restrict__ scb,
                                              float* __restrict__ out) {
    int b = blockIdx.x;
    int h = threadIdx.x;
    __shared__ float ctx[DN];
    __shared__ float sl[HN];
    __shared__ float sl2[HN];
    __shared__ float yv[HN];
    sl[h] = s[b * HN + h];
    float c0a = 0.f, c1a = 0.f;
#pragma unroll
    for (int j = 0; j < 16; j++) {
        c0a += part[((size_t)b * 16 + j) * DN + h];
        c1a += part[((size_t)b * 16 + j) * DN + h + HN];
    }
    ctx[h] = c0a;
    ctx[h + HN] = c1a;
    __syncthreads();
    int tgt = target[b * NSTEPS + t];
    const float* ys = Lys + (size_t)tgt * G4;
    float ri = ys[h] + Lgsb[h];
    float rf = ys[h + HN] + Lgsb[h + HN];
    float rg = ys[h + 2 * HN] + Lgsb[h + 2 * HN];
    float ro = ys[h + 3 * HN] + Lgsb[h + 3 * HN];
    for (int k = 0; k < HN; k++) {
        float sv = sl[k];
        const float* row = Lss + (size_t)k * G4;
        ri = fmaf(sv, row[h], ri);
        rf = fmaf(sv, row[h + HN], rf);
        rg = fmaf(sv, row[h + 2 * HN], rg);
        ro = fmaf(sv, row[h + 3 * HN], ro);
    }
    for (int k = 0; k < DN; k++) {
        float cv = ctx[k];
        const float* row = Lgs + (size_t)k * G4;
        ri = fmaf(cv, row[h], ri);
        rf = fmaf(cv, row[h + HN], rf);
        rg = fmaf(cv, row[h + 2 * HN], rg);
        ro = fmaf(cv, row[h + 3 * HN], ro);
    }
    float sig_i = 1.f / (1.f + expf(-ri));
    float sig_f = 1.f / (1.f + expf(-rf));
    float sig_o = 1.f / (1.f + expf(-ro));
    float cn = sig_f * c[b * HN + h] + sig_i * tanhf(rg);
    float sn = sig_o * tanhf(cn);
    c[b * HN + h] = cn;
    s[b * HN + h] = sn;
    sl2[h] = sn;
    __syncthreads();
    // y gate
    float acc = Lgyb[h];
    for (int d = 0; d < DN; d++) acc = fmaf(ctx[d], Lgy[(size_t)d * HN + h], acc);
    for (int k = 0; k < HN; k++) acc = fmaf(sl2[k], Lsy[(size_t)k * HN + h], acc);
    yv[h] = tanhf(acc);
    // next-step projections sm/sc from s_new
    float a1 = Wsmb[h], a2 = Wsmb[h + HN], a3 = Wscb[h], a4 = Wscb[h + HN];
    for (int k = 0; k < HN; k++) {
        float sv = sl2[k];
        a1 = fmaf(sv, Wsm[(size_t)k * DN + h], a1);
        a2 = fmaf(sv, Wsm[(size_t)k * DN + h + HN], a2);
        a3 = fmaf(sv, Wsc[(size_t)k * DN + h], a3);
        a4 = fmaf(sv, Wsc[(size_t)k * DN + h + HN], a4);
    }
    smb[b * DN + h] = a1;
    smb[b * DN + h + HN] = a2;
    scb[b * DN + h] = a3;
    scb[b * DN + h + HN] = a4;
    __syncthreads();
    // output projection
    float* ob = out + ((size_t)b * NSTEPS + t) * CCLS;
    for (int cc = h; cc < CCLS; cc += HN) {
        float a = Lyyb[cc];
        for (int k = 0; k < HN; k++) a = fmaf(yv[k], Lyy[(size_t)k * CCLS + cc], a);
        ob[cc] = a;
    }
}

extern "C" void kernel_launch(void* const* d_in, const int* in_sizes, int n_in,
                              void* d_out, int out_size, void* d_ws, size_t ws_size,
                              hipStream_t stream) {
    const float* enc  = (const float*)d_in[0];
    const int*   target = (const int*)d_in[1];
    const int*   len  = (const int*)d_in[2];
    const float* noise = (const float*)d_in[3];
    const float* Wsm  = (const float*)d_in[4];
    const float* Wsmb = (const float*)d_in[5];
    const float* WhM  = (const float*)d_in[6];
    const float* vM   = (const float*)d_in[7];
    const float* g    = (const float*)d_in[8];
    const float* rm   = (const float*)d_in[9];
    const float* Wsc  = (const float*)d_in[10];
    const float* Wscb = (const float*)d_in[11];
    const float* WhC  = (const float*)d_in[12];
    const float* vC   = (const float*)d_in[13];
    const float* Lsy  = (const float*)d_in[14];
    const float* Lgy  = (const float*)d_in[15];
    const float* Lgyb = (const float*)d_in[16];
    const float* Lyy  = (const float*)d_in[17];
    const float* Lyyb = (const float*)d_in[18];
    const float* Lys  = (const float*)d_in[19];
    const float* Lss  = (const float*)d_in[20];
    const float* Lgs  = (const float*)d_in[21];
    const float* Lgsb = (const float*)d_in[22];
    float* out = (float*)d_out;

    char* w = (char*)d_ws;
    size_t off = 0;
    auto alloc = [&](size_t bytes) { void* pp = w + off; off += (bytes + 255) & ~(size_t)255; return pp; };
    _Float16* A16   = (_Float16*)alloc((size_t)BB * SS * DN * 2);
    _Float16* WcT   = (_Float16*)alloc((size_t)1024 * 512 * 2);
    _Float16* encMC = (_Float16*)alloc((size_t)BB * SS * 1024 * 2);
    float* smb   = (float*)alloc(BB * DN * 4);
    float* scb   = (float*)alloc(BB * DN * 4);
    float* pbuf  = (float*)alloc(BB * SS * 4);
    float* ech   = (float*)alloc(BB * SS * 4);
    float* aA    = (float*)alloc(BB * SS * 4);
    float* aBf   = (float*)alloc(BB * SS * 4);
    float* betab = (float*)alloc(BB * SS * 4);
    float* part  = (float*)alloc((size_t)BB * 16 * DN * 4);
    float* sbuf  = (float*)alloc(BB * HN * 4);
    float* cbuf  = (float*)alloc(BB * HN * 4);
    float* vn    = (float*)alloc(16);
    (void)ws_size; (void)in_sizes; (void)n_in; (void)out_size;

    vnorm_k<<<1, 512, 0, stream>>>(vM, g, vn);
    conv_enc_k<<<4096, 256, 0, stream>>>(enc, A16);
    convW_k<<<dim3(16, 32), 256, 0, stream>>>(WhM, WhC, WcT);
    gemm16_k<<<dim3(128, 8), 256, 0, stream>>>(A16, WcT, encMC);
    hipMemsetAsync(sbuf, 0, BB * HN * sizeof(float), stream);
    hipMemsetAsync(cbuf, 0, BB * HN * sizeof(float), stream);
    hipMemsetAsync(aA, 0, BB * SS * sizeof(float), stream);
    inita_k<<<1, 64, 0, stream>>>(aA);
    proj_k<<<BB, 512, 0, stream>>>(sbuf, Wsm, Wsmb, Wsc, Wscb, smb, scb);

    for (int t = 0; t < NSTEPS; t++) {
        float* ain  = (t % 2 == 0) ? aA : aBf;
        float* aout = (t % 2 == 0) ? aBf : aA;
        energy_k<<<BB * SS / 4, 256, 0, stream>>>(encMC, smb, scb, vM, vC, vn, rm,
                                                  len, noise + (size_t)t * BB * SS, pbuf, ech);
        scanrow_k<<<BB, 1024, 0, stream>>>(pbuf, ain, ech, aout, betab);
        ctxpart_k<<<dim3(BB, 16), 512, 0, stream>>>(betab, A16, part);
        tail_k<<<BB, 256, 0, stream>>>(part, target, t, Lys, Lss, Lgs, Lgsb,
                                       Lgy, Lgyb, Lsy, Lyy, Lyyb,
                                       Wsm, Wsmb, Wsc, Wscb,
                                       sbuf, cbuf, smb, scb, out);
    }
}

// Round 3
// 595.726 us; speedup vs baseline: 2.3217x; 1.9014x over previous
//
#include <hip/hip_runtime.h>
#include <math.h>
#include <float.h>

#define HN 256
#define DN 512
#define CCLS 1000
#define BB 16
#define SS 1024
#define NSTEPS 8
#define G4 1024   // 4*H
#define KV 768    // s(256) + ctx(512)

using f16x8 = __attribute__((ext_vector_type(8))) _Float16;
using f32x4 = __attribute__((ext_vector_type(4))) float;

__device__ __forceinline__ void gload_lds16(const void* g, void* l) {
    __builtin_amdgcn_global_load_lds((const __attribute__((address_space(1))) void*)g,
                                     (__attribute__((address_space(3))) void*)l, 16, 0, 0);
}

// ---------------- v_norm = g / ||v_mono|| ----------------
__global__ __launch_bounds__(512) void vnorm_k(const float* __restrict__ v,
                                               const float* __restrict__ g,
                                               float* __restrict__ out) {
    __shared__ float red[512];
    int t = threadIdx.x;
    float x = v[t];
    red[t] = x * x;
    __syncthreads();
    for (int off = 256; off > 0; off >>= 1) {
        if (t < off) red[t] += red[t + off];
        __syncthreads();
    }
    if (t == 0) out[0] = g[0] / sqrtf(red[0]);
}

// ---------------- f32 -> f16 conversion of enc ----------------
__global__ __launch_bounds__(256) void conv_enc_k(const float* __restrict__ in,
                                                  _Float16* __restrict__ out) {
    size_t i = ((size_t)blockIdx.x * 256 + threadIdx.x) * 8;
    float4 a = *(const float4*)(in + i);
    float4 b = *(const float4*)(in + i + 4);
    f16x8 o;
    o[0] = (_Float16)a.x; o[1] = (_Float16)a.y; o[2] = (_Float16)a.z; o[3] = (_Float16)a.w;
    o[4] = (_Float16)b.x; o[5] = (_Float16)b.y; o[6] = (_Float16)b.z; o[7] = (_Float16)b.w;
    *(f16x8*)(out + i) = o;
}

// ---------------- build WcT [1024][512] f16 = transpose of [W1 | W2] ----------------
__global__ __launch_bounds__(256) void convW_k(const float* __restrict__ W1,
                                               const float* __restrict__ W2,
                                               _Float16* __restrict__ WcT) {
    int kt = blockIdx.x;   // 16 tiles over K=512
    int nt = blockIdx.y;   // 32 tiles over N=1024
    __shared__ _Float16 tile[32][33];
    int tx = threadIdx.x & 31, ty = threadIdx.x >> 5;   // ty 0..7
    int n0 = nt * 32, k0 = kt * 32;
    for (int r = 0; r < 32; r += 8) {
        int k = k0 + ty + r, n = n0 + tx;
        float v = (n < 512) ? W1[(size_t)k * 512 + n] : W2[(size_t)k * 512 + (n - 512)];
        tile[tx][ty + r] = (_Float16)v;
    }
    __syncthreads();
    for (int r = 0; r < 32; r += 8) {
        int n = n0 + ty + r, k = k0 + tx;
        WcT[(size_t)n * 512 + k] = tile[ty + r][tx];
    }
}

// ---------------- generic f32 transpose: dst[c][coloff + r] = src[r][c] ----------------
__global__ __launch_bounds__(256) void trans_k(const float* __restrict__ src, int R, int C,
                                               float* __restrict__ dst, int dstride, int coloff) {
    __shared__ float tile[32][33];
    int c0 = blockIdx.x * 32, r0 = blockIdx.y * 32;
    int tx = threadIdx.x & 31, ty = threadIdx.x >> 5;
    for (int rr = 0; rr < 32; rr += 8) {
        int r = r0 + ty + rr, cc = c0 + tx;
        tile[ty + rr][tx] = (r < R && cc < C) ? src[(size_t)r * C + cc] : 0.f;
    }
    __syncthreads();
    for (int rr = 0; rr < 32; rr += 8) {
        int cc = c0 + ty + rr, r = r0 + tx;
        if (cc < C && r < R) dst[(size_t)cc * dstride + coloff + r] = tile[tx][ty + rr];
    }
}

// ---------------- f16 MFMA GEMM: encMC[16384][1024] = A16 @ WcT^T ----------------
__global__ __launch_bounds__(256) void gemm16_k(const _Float16* __restrict__ A16,
                                                const _Float16* __restrict__ WcT,
                                                _Float16* __restrict__ encMC) {
    __shared__ _Float16 Alds[128 * 32];
    __shared__ _Float16 Blds[128 * 32];
    int bm = blockIdx.x;
    int bn = blockIdx.y;
    int tid = threadIdx.x;
    int lane = tid & 63;
    int w = tid >> 6;
    int wr = w >> 1, wc = w & 1;
    int lr = lane & 15;
    int kg = lane >> 4;
    f32x4 acc[4][4];
#pragma unroll
    for (int i = 0; i < 4; i++)
#pragma unroll
        for (int j = 0; j < 4; j++) acc[i][j] = (f32x4){0.f, 0.f, 0.f, 0.f};

    int wavebase = tid & ~63;
    for (int k0 = 0; k0 < 512; k0 += 32) {
        __syncthreads();
#pragma unroll
        for (int is = 0; is < 2; is++) {
            int l = is * 256 + tid;
            int row = l >> 2, kgs = l & 3;
            int kp = kgs ^ ((row ^ (row >> 2)) & 3);
            gload_lds16(A16 + (size_t)(bm * 128 + row) * 512 + k0 + kp * 8,
                        (char*)Alds + (size_t)(is * 256 + wavebase) * 16);
            gload_lds16(WcT + (size_t)(bn * 128 + row) * 512 + k0 + kp * 8,
                        (char*)Blds + (size_t)(is * 256 + wavebase) * 16);
        }
        __syncthreads();
        f16x8 af[4], bf[4];
#pragma unroll
        for (int mi = 0; mi < 4; mi++) {
            int r = wr * 64 + mi * 16 + lr;
            int kp = kg ^ ((r ^ (r >> 2)) & 3);
            af[mi] = *(const f16x8*)(Alds + r * 32 + kp * 8);
        }
#pragma unroll
        for (int ni = 0; ni < 4; ni++) {
            int cgl = wc * 64 + ni * 16 + lr;
            int kp = kg ^ ((cgl ^ (cgl >> 2)) & 3);
            bf[ni] = *(const f16x8*)(Blds + cgl * 32 + kp * 8);
        }
#pragma unroll
        for (int mi = 0; mi < 4; mi++)
#pragma unroll
            for (int ni = 0; ni < 4; ni++)
                acc[mi][ni] = __builtin_amdgcn_mfma_f32_16x16x32_f16(af[mi], bf[ni], acc[mi][ni], 0, 0, 0);
    }
    int cr = lane >> 4;
#pragma unroll
    for (int mi = 0; mi < 4; mi++)
#pragma unroll
        for (int ni = 0; ni < 4; ni++) {
            int col = bn * 128 + wc * 64 + ni * 16 + lr;
#pragma unroll
            for (int j = 0; j < 4; j++) {
                int row = bm * 128 + wr * 64 + mi * 16 + cr * 4 + j;
                encMC[(size_t)row * 1024 + col] = (_Float16)acc[mi][ni][j];
            }
        }
}

// ---------------- a0 / bias inits ----------------
__global__ void inita_k(float* __restrict__ a) {
    int b = threadIdx.x;
    if (b < BB) a[(size_t)b * SS] = 1.f;
}

__global__ __launch_bounds__(512) void initb_k(const float* __restrict__ Wsmb, const float* __restrict__ Wscb,
                                               float* __restrict__ smb, float* __restrict__ scb) {
    int b = blockIdx.x, d = threadIdx.x;
    smb[b * DN + d] = Wsmb[d];
    scb[b * DN + d] = Wscb[d];
}

// ---------------- energies: one wave per (b,s) row ----------------
__global__ __launch_bounds__(256) void energy_k(const _Float16* __restrict__ encMC,
                                                const float* __restrict__ sm, const float* __restrict__ sc,
                                                const float* __restrict__ vM, const float* __restrict__ vC,
                                                const float* __restrict__ vnorm, const float* __restrict__ rmono,
                                                const int* __restrict__ len, const float* __restrict__ noise_t,
                                                float* __restrict__ p, float* __restrict__ ech) {
    int wave = blockIdx.x * 4 + (threadIdx.x >> 6);
    int lane = threadIdx.x & 63;
    int b = wave >> 10;
    int si = wave & 1023;
    const f16x8* row = (const f16x8*)(encMC + (size_t)wave * 1024);
    f16x8 em = row[lane];
    f16x8 ec = row[64 + lane];
    int d0 = lane * 8;
    float4 sma = *(const float4*)&sm[b * DN + d0];
    float4 smbv = *(const float4*)&sm[b * DN + d0 + 4];
    float4 sca = *(const float4*)&sc[b * DN + d0];
    float4 scbv = *(const float4*)&sc[b * DN + d0 + 4];
    float4 vma = *(const float4*)&vM[d0];
    float4 vmb = *(const float4*)&vM[d0 + 4];
    float4 vca = *(const float4*)&vC[d0];
    float4 vcb = *(const float4*)&vC[d0 + 4];
    float smv[8] = {sma.x, sma.y, sma.z, sma.w, smbv.x, smbv.y, smbv.z, smbv.w};
    float scv[8] = {sca.x, sca.y, sca.z, sca.w, scbv.x, scbv.y, scbv.z, scbv.w};
    float vmv[8] = {vma.x, vma.y, vma.z, vma.w, vmb.x, vmb.y, vmb.z, vmb.w};
    float vcv[8] = {vca.x, vca.y, vca.z, vca.w, vcb.x, vcb.y, vcb.z, vcb.w};
    float s1 = 0.f, s2 = 0.f;
#pragma unroll
    for (int j = 0; j < 8; j++) {
        s1 += tanhf((float)em[j] + smv[j]) * vmv[j];
        s2 += tanhf((float)ec[j] + scv[j]) * vcv[j];
    }
#pragma unroll
    for (int off = 32; off > 0; off >>= 1) {
        s1 += __shfl_xor(s1, off);
        s2 += __shfl_xor(s2, off);
    }
    if (lane == 0) {
        bool masked = (si >= len[b]);
        float pe;
        if (masked) {
            pe = 0.f;
        } else {
            float e = vnorm[0] * s1 + rmono[0] + noise_t[b * SS + si];
            pe = 1.f / (1.f + expf(-e));
        }
        p[b * SS + si] = pe;
        ech[b * SS + si] = masked ? -INFINITY : s2;
    }
}

// ---------------- per-row scan: alpha recurrence + chunk softmax + beta ----------------
__global__ __launch_bounds__(1024) void scanrow_k(const float* __restrict__ p,
                                                  const float* __restrict__ aprev,
                                                  const float* __restrict__ ech,
                                                  float* __restrict__ anew,
                                                  float* __restrict__ beta) {
    int b = blockIdx.x;
    int i = threadIdx.x;
    int lane = i & 63, w = i >> 6;
    __shared__ float wred[16];
    __shared__ float wred2[16];
    __shared__ float mred[16];
    __shared__ float exS[SS];
    __shared__ float rS[SS];
    float pi = p[b * SS + i];
    float lf = (i < SS - 1) ? logf(fminf(fmaxf(1.f - pi, 1e-8f), 1.f)) : 0.f;
    float x = lf;
#pragma unroll
    for (int off = 1; off < 64; off <<= 1) {
        float n = __shfl_up(x, off);
        if (lane >= off) x += n;
    }
    if (lane == 63) wred[w] = x;
    float e = ech[b * SS + i];
    float mx = e;
#pragma unroll
    for (int off = 32; off > 0; off >>= 1) mx = fmaxf(mx, __shfl_xor(mx, off));
    if (lane == 0) mred[w] = mx;
    __syncthreads();
    float base = 0.f;
    for (int j = 0; j < 16; j++)
        if (j < w) base += wred[j];
    float csum = base + x;
    float cpp = expf(csum - lf);
    float u = aprev[b * SS + i] / fminf(fmaxf(cpp, 1e-8f), 1.f);
    float m = mred[0];
    for (int j = 1; j < 16; j++) m = fmaxf(m, mred[j]);
    float x2 = u;
#pragma unroll
    for (int off = 1; off < 64; off <<= 1) {
        float n = __shfl_up(x2, off);
        if (lane >= off) x2 += n;
    }
    if (lane == 63) wred2[w] = x2;
    __syncthreads();
    float base2 = 0.f;
    for (int j = 0; j < 16; j++)
        if (j < w) base2 += wred2[j];
    float q = cpp * (base2 + x2);
    float alpha = fminf(fmaxf(pi * q, 1e-8f), 1.f);
    anew[b * SS + i] = alpha;
    float ex = fmaxf(expf(e - m), 1e-5f);
    exS[i] = ex;
    __syncthreads();
    float denom = ex;
    if (i >= 1) denom += exS[i - 1];
    if (i >= 2) denom += exS[i - 2];
    if (i >= 3) denom += exS[i - 3];
    denom = fmaxf(denom, 1e-10f);
    rS[i] = alpha / denom;
    __syncthreads();
    float bsum = rS[i];
    if (i + 1 < SS) bsum += rS[i + 1];
    if (i + 2 < SS) bsum += rS[i + 2];
    if (i + 3 < SS) bsum += rS[i + 3];
    beta[b * SS + i] = ex * bsum;
}

// ---------------- ctx partial over f16 enc copy ----------------
__global__ __launch_bounds__(512) void ctxpart_k(const float* __restrict__ beta,
                                                 const _Float16* __restrict__ enc16,
                                                 float* __restrict__ part) {
    int b = blockIdx.x, scN = blockIdx.y;
    int d = threadIdx.x;
    int s0 = scN * 64;
    float acc = 0.f;
    const _Float16* eb = enc16 + ((size_t)(b * SS + s0)) * DN + d;
    const float* bb_ = beta + b * SS + s0;
#pragma unroll 4
    for (int s = 0; s < 64; s++) acc = fmaf(bb_[s], (float)eb[(size_t)s * DN], acc);
    part[((size_t)b * 16 + scN) * DN + d] = acc;
}

// ---------------- ctx reduce -> sctx ctx region ----------------
__global__ __launch_bounds__(512) void ctxred_k(const float* __restrict__ part,
                                                float* __restrict__ sctx) {
    int b = blockIdx.x;
    int d = threadIdx.x;
    float acc = 0.f;
#pragma unroll
    for (int j = 0; j < 16; j++) acc += part[((size_t)b * 16 + j) * DN + d];
    sctx[b * KV + HN + d] = acc;
}

// ---------------- gates: rec[b][n] = s@Lss + ctx@Lgs (cols via transposed WgT) ----------------
__global__ __launch_bounds__(256) void gates_k(const float* __restrict__ sctx,
                                               const float* __restrict__ WgT,
                                               float* __restrict__ rec) {
    __shared__ float sl[BB * KV];
    int tid = threadIdx.x;
    for (int i = tid * 4; i < BB * KV; i += 1024)
        *(float4*)&sl[i] = *(const float4*)&sctx[i];
    __syncthreads();
    int wave = tid >> 6, lane = tid & 63;
    int n0 = (blockIdx.x * 4 + wave) * 2;
    float acc0[BB] = {0.f}, acc1[BB] = {0.f};
    const float* w0p = WgT + (size_t)n0 * KV;
    const float* w1p = w0p + KV;
#pragma unroll
    for (int j = 0; j < 12; j++) {
        int e = lane + j * 64;
        float w0 = w0p[e], w1 = w1p[e];
#pragma unroll
        for (int b = 0; b < BB; b++) {
            float xv = sl[b * KV + e];
            acc0[b] = fmaf(w0, xv, acc0[b]);
            acc1[b] = fmaf(w1, xv, acc1[b]);
        }
    }
#pragma unroll
    for (int b = 0; b < BB; b++)
#pragma unroll
        for (int off = 32; off > 0; off >>= 1) {
            acc0[b] += __shfl_xor(acc0[b], off);
            acc1[b] += __shfl_xor(acc1[b], off);
        }
    if (lane == 0) {
#pragma unroll
        for (int b = 0; b < BB; b++) {
            rec[b * G4 + n0] = acc0[b];
            rec[b * G4 + n0 + 1] = acc1[b];
        }
    }
}

// ---------------- LSTM elementwise (+ Lys gather + Lgs bias) ----------------
__global__ __launch_bounds__(256) void lstm_k(const float* __restrict__ rec,
                                              const int* __restrict__ target, int t,
                                              const float* __restrict__ Lys, const float* __restrict__ Lgsb,
                                              float* __restrict__ c, float* __restrict__ sctx) {
    int b = blockIdx.x, h = threadIdx.x;
    int tgt = target[b * NSTEPS + t];
    const float* ys = Lys + (size_t)tgt * G4;
    float ri = rec[b * G4 + h]          + ys[h]          + Lgsb[h];
    float rf = rec[b * G4 + h + HN]     + ys[h + HN]     + Lgsb[h + HN];
    float rg = rec[b * G4 + h + 2 * HN] + ys[h + 2 * HN] + Lgsb[h + 2 * HN];
    float ro = rec[b * G4 + h + 3 * HN] + ys[h + 3 * HN] + Lgsb[h + 3 * HN];
    float sig_i = 1.f / (1.f + expf(-ri));
    float sig_f = 1.f / (1.f + expf(-rf));
    float sig_o = 1.f / (1.f + expf(-ro));
    float cn = sig_f * c[b * HN + h] + sig_i * tanhf(rg);
    float sn = sig_o * tanhf(cn);
    c[b * HN + h] = cn;
    sctx[b * KV + h] = sn;
}

// ---------------- post1: y gate (blocks 0..15) + next-step proj (blocks 16..79) ----------------
__global__ __launch_bounds__(256) void post1_k(const float* __restrict__ sctx,
                                               const float* __restrict__ WyT, const float* __restrict__ Lgyb,
                                               const float* __restrict__ WpT,
                                               const float* __restrict__ Wsmb, const float* __restrict__ Wscb,
                                               float* __restrict__ yv,
                                               float* __restrict__ smb, float* __restrict__ scb) {
    __shared__ float sl[BB * KV];
    int tid = threadIdx.x;
    for (int i = tid * 4; i < BB * KV; i += 1024)
        *(float4*)&sl[i] = *(const float4*)&sctx[i];
    __syncthreads();
    int wave = tid >> 6, lane = tid & 63;
    if (blockIdx.x < 16) {
        // y: 256 cols, K=768
        int h0 = blockIdx.x * 16 + wave * 4;
        for (int q = 0; q < 4; q++) {
            int h = h0 + q;
            const float* wp = WyT + (size_t)h * KV;
            float acc[BB] = {0.f};
#pragma unroll
            for (int j = 0; j < 12; j++) {
                int e = lane + j * 64;
                float wv = wp[e];
#pragma unroll
                for (int b = 0; b < BB; b++) acc[b] = fmaf(wv, sl[b * KV + e], acc[b]);
            }
#pragma unroll
            for (int b = 0; b < BB; b++)
#pragma unroll
                for (int off = 32; off > 0; off >>= 1) acc[b] += __shfl_xor(acc[b], off);
            if (lane == 0) {
#pragma unroll
                for (int b = 0; b < BB; b++) yv[b * HN + h] = tanhf(acc[b] + Lgyb[h]);
            }
        }
    } else {
        // proj: 1024 cols (sm 0..511, sc 512..1023), K=256 (s part only)
        int j0 = (blockIdx.x - 16) * 16 + wave * 4;
        for (int q = 0; q < 4; q++) {
            int jc = j0 + q;
            const float* wp = WpT + (size_t)jc * HN;
            float acc[BB] = {0.f};
#pragma unroll
            for (int k = 0; k < 4; k++) {
                int e = lane + k * 64;
                float wv = wp[e];
#pragma unroll
                for (int b = 0; b < BB; b++) acc[b] = fmaf(wv, sl[b * KV + e], acc[b]);
            }
#pragma unroll
            for (int b = 0; b < BB; b++)
#pragma unroll
                for (int off = 32; off > 0; off >>= 1) acc[b] += __shfl_xor(acc[b], off);
            if (lane == 0) {
                if (jc < DN) {
#pragma unroll
                    for (int b = 0; b < BB; b++) smb[b * DN + jc] = acc[b] + Wsmb[jc];
                } else {
                    int jj = jc - DN;
#pragma unroll
                    for (int b = 0; b < BB; b++) scb[b * DN + jj] = acc[b] + Wscb[jj];
                }
            }
        }
    }
}

// ---------------- output projection: 1000 cols, K=256 ----------------
__global__ __launch_bounds__(256) void out_k(const float* __restrict__ yv,
                                             const float* __restrict__ LyyT, const float* __restrict__ Lyyb,
                                             float* __restrict__ out, int t) {
    __shared__ float sl[BB * HN];
    int tid = threadIdx.x;
    for (int i = tid * 4; i < BB * HN; i += 1024)
        *(float4*)&sl[i] = *(const float4*)&yv[i];
    __syncthreads();
    int wave = tid >> 6, lane = tid & 63;
    int c0 = (blockIdx.x * 4 + wave) * 4;
    for (int q = 0; q < 4; q++) {
        int cc = c0 + q;
        if (cc >= CCLS) break;
        const float* wp = LyyT + (size_t)cc * HN;
        float acc[BB] = {0.f};
#pragma unroll
        for (int k = 0; k < 4; k++) {
            int e = lane + k * 64;
            float wv = wp[e];
#pragma unroll
            for (int b = 0; b < BB; b++) acc[b] = fmaf(wv, sl[b * HN + e], acc[b]);
        }
#pragma unroll
        for (int b = 0; b < BB; b++)
#pragma unroll
            for (int off = 32; off > 0; off >>= 1) acc[b] += __shfl_xor(acc[b], off);
        if (lane == 0) {
            float bias = Lyyb[cc];
#pragma unroll
            for (int b = 0; b < BB; b++) out[((size_t)b * NSTEPS + t) * CCLS + cc] = acc[b] + bias;
        }
    }
}

extern "C" void kernel_launch(void* const* d_in, const int* in_sizes, int n_in,
                              void* d_out, int out_size, void* d_ws, size_t ws_size,
                              hipStream_t stream) {
    const float* enc  = (const float*)d_in[0];
    const int*   target = (const int*)d_in[1];
    const int*   len  = (const int*)d_in[2];
    const float* noise = (const float*)d_in[3];
    const float* Wsm  = (const float*)d_in[4];
    const float* Wsmb = (const float*)d_in[5];
    const float* WhM  = (const float*)d_in[6];
    const float* vM   = (const float*)d_in[7];
    const float* g    = (const float*)d_in[8];
    const float* rm   = (const float*)d_in[9];
    const float* Wsc  = (const float*)d_in[10];
    const float* Wscb = (const float*)d_in[11];
    const float* WhC  = (const float*)d_in[12];
    const float* vC   = (const float*)d_in[13];
    const float* Lsy  = (const float*)d_in[14];
    const float* Lgy  = (const float*)d_in[15];
    const float* Lgyb = (const float*)d_in[16];
    const float* Lyy  = (const float*)d_in[17];
    const float* Lyyb = (const float*)d_in[18];
    const float* Lys  = (const float*)d_in[19];
    const float* Lss  = (const float*)d_in[20];
    const float* Lgs  = (const float*)d_in[21];
    const float* Lgsb = (const float*)d_in[22];
    float* out = (float*)d_out;

    char* w = (char*)d_ws;
    size_t off = 0;
    auto alloc = [&](size_t bytes) { void* pp = w + off; off += (bytes + 255) & ~(size_t)255; return pp; };
    _Float16* A16   = (_Float16*)alloc((size_t)BB * SS * DN * 2);
    _Float16* WcT   = (_Float16*)alloc((size_t)1024 * 512 * 2);
    _Float16* encMC = (_Float16*)alloc((size_t)BB * SS * 1024 * 2);
    float* WgT  = (float*)alloc((size_t)G4 * KV * 4);     // [1024][768]
    float* WyT  = (float*)alloc((size_t)HN * KV * 4);     // [256][768]
    float* WpT  = (float*)alloc((size_t)G4 * HN * 4);     // [1024][256]
    float* LyyT = (float*)alloc((size_t)CCLS * HN * 4);   // [1000][256]
    float* smb   = (float*)alloc(BB * DN * 4);
    float* scb   = (float*)alloc(BB * DN * 4);
    float* pbuf  = (float*)alloc(BB * SS * 4);
    float* ech   = (float*)alloc(BB * SS * 4);
    float* aA    = (float*)alloc(BB * SS * 4);
    float* aBf   = (float*)alloc(BB * SS * 4);
    float* betab = (float*)alloc(BB * SS * 4);
    float* part  = (float*)alloc((size_t)BB * 16 * DN * 4);
    float* sctx  = (float*)alloc((size_t)BB * KV * 4);
    float* rec   = (float*)alloc((size_t)BB * G4 * 4);
    float* yvb   = (float*)alloc((size_t)BB * HN * 4);
    float* cbuf  = (float*)alloc(BB * HN * 4);
    float* vn    = (float*)alloc(16);
    (void)ws_size; (void)in_sizes; (void)n_in; (void)out_size;

    // ---- preamble ----
    vnorm_k<<<1, 512, 0, stream>>>(vM, g, vn);
    conv_enc_k<<<4096, 256, 0, stream>>>(enc, A16);
    convW_k<<<dim3(16, 32), 256, 0, stream>>>(WhM, WhC, WcT);
    gemm16_k<<<dim3(128, 8), 256, 0, stream>>>(A16, WcT, encMC);
    // transposed weights: WgT[n][k] = k<256 ? Lss[k][n] : Lgs[k-256][n]
    trans_k<<<dim3(32, 8),  256, 0, stream>>>(Lss, HN, G4, WgT, KV, 0);
    trans_k<<<dim3(32, 16), 256, 0, stream>>>(Lgs, DN, G4, WgT, KV, HN);
    trans_k<<<dim3(8, 8),   256, 0, stream>>>(Lsy, HN, HN, WyT, KV, 0);
    trans_k<<<dim3(8, 16),  256, 0, stream>>>(Lgy, DN, HN, WyT, KV, HN);
    trans_k<<<dim3(16, 8),  256, 0, stream>>>(Wsm, HN, DN, WpT, HN, 0);
    trans_k<<<dim3(16, 8),  256, 0, stream>>>(Wsc, HN, DN, WpT + (size_t)DN * HN, HN, 0);
    trans_k<<<dim3(32, 8),  256, 0, stream>>>(Lyy, HN, CCLS, LyyT, HN, 0);
    hipMemsetAsync(sctx, 0, (size_t)BB * KV * sizeof(float), stream);
    hipMemsetAsync(cbuf, 0, BB * HN * sizeof(float), stream);
    hipMemsetAsync(aA, 0, BB * SS * sizeof(float), stream);
    inita_k<<<1, 64, 0, stream>>>(aA);
    initb_k<<<BB, 512, 0, stream>>>(Wsmb, Wscb, smb, scb);

    for (int t = 0; t < NSTEPS; t++) {
        float* ain  = (t % 2 == 0) ? aA : aBf;
        float* aout = (t % 2 == 0) ? aBf : aA;
        energy_k<<<BB * SS / 4, 256, 0, stream>>>(encMC, smb, scb, vM, vC, vn, rm,
                                                  len, noise + (size_t)t * BB * SS, pbuf, ech);
        scanrow_k<<<BB, 1024, 0, stream>>>(pbuf, ain, ech, aout, betab);
        ctxpart_k<<<dim3(BB, 16), 512, 0, stream>>>(betab, A16, part);
        ctxred_k<<<BB, 512, 0, stream>>>(part, sctx);
        gates_k<<<128, 256, 0, stream>>>(sctx, WgT, rec);
        lstm_k<<<BB, 256, 0, stream>>>(rec, target, t, Lys, Lgsb, cbuf, sctx);
        post1_k<<<80, 256, 0, stream>>>(sctx, WyT, Lgyb, WpT, Wsmb, Wscb, yvb, smb, scb);
        out_k<<<63, 256, 0, stream>>>(yvb, LyyT, Lyyb, out, t);
    }
}

// Round 5
// 563.083 us; speedup vs baseline: 2.4563x; 1.0580x over previous
//
#include <hip/hip_runtime.h>
#include <math.h>
#include <float.h>

#define HN 256
#define DN 512
#define CCLS 1000
#define BB 16
#define SS 1024
#define NSTEPS 8
#define G4 1024   // 4*H
#define KV 768    // s(256) + ctx(512)

using f16x8 = __attribute__((ext_vector_type(8))) _Float16;
using f32x4 = __attribute__((ext_vector_type(4))) float;

__device__ __forceinline__ void gload_lds16(const void* g, void* l) {
    __builtin_amdgcn_global_load_lds((const __attribute__((address_space(1))) void*)g,
                                     (__attribute__((address_space(3))) void*)l, 16, 0, 0);
}

// NaN-safe fast tanh: 1 - 2/(e^{2x}+1); e=inf -> 1, e=0 -> -1
__device__ __forceinline__ float ftanh(float x) {
    float e = __expf(2.f * x);
    return 1.f - 2.f / (e + 1.f);
}
__device__ __forceinline__ float fsigm(float x) {
    return 1.f / (1.f + __expf(-x));
}

// ---------------- init: aA, sctxA, cbuf, smb, scb, vnorm ----------------
__global__ __launch_bounds__(512) void init_k(const float* __restrict__ vM, const float* __restrict__ g,
                                              const float* __restrict__ Wsmb, const float* __restrict__ Wscb,
                                              float* __restrict__ aA, float* __restrict__ sctxA,
                                              float* __restrict__ cbuf,
                                              float* __restrict__ smb, float* __restrict__ scb,
                                              float* __restrict__ vn) {
    int bid = blockIdx.x, t = threadIdx.x;
    if (bid == 96) {
        __shared__ float red[512];
        float x = vM[t];
        red[t] = x * x;
        __syncthreads();
        for (int off = 256; off > 0; off >>= 1) {
            if (t < off) red[t] += red[t + off];
            __syncthreads();
        }
        if (t == 0) vn[0] = g[0] / sqrtf(red[0]);
        return;
    }
    int i = bid * 512 + t;
    if (i < 16384) {
        aA[i] = ((i & (SS - 1)) == 0) ? 1.f : 0.f;
    } else if (i < 28672) {
        sctxA[i - 16384] = 0.f;
    } else if (i < 32768) {
        cbuf[i - 28672] = 0.f;
    } else if (i < 40960) {
        int j = i - 32768;
        smb[j] = Wsmb[j & (DN - 1)];
    } else {
        int j = i - 40960;
        scb[j] = Wscb[j & (DN - 1)];
    }
}

// ---------------- f32 -> f16 conversion of enc ----------------
__global__ __launch_bounds__(256) void conv_enc_k(const float* __restrict__ in,
                                                  _Float16* __restrict__ out) {
    size_t i = ((size_t)blockIdx.x * 256 + threadIdx.x) * 8;
    float4 a = *(const float4*)(in + i);
    float4 b = *(const float4*)(in + i + 4);
    f16x8 o;
    o[0] = (_Float16)a.x; o[1] = (_Float16)a.y; o[2] = (_Float16)a.z; o[3] = (_Float16)a.w;
    o[4] = (_Float16)b.x; o[5] = (_Float16)b.y; o[6] = (_Float16)b.z; o[7] = (_Float16)b.w;
    *(f16x8*)(out + i) = o;
}

// ---------------- build WcT [1024][512] f16 = transpose of [W1 | W2] ----------------
__global__ __launch_bounds__(256) void convW_k(const float* __restrict__ W1,
                                               const float* __restrict__ W2,
                                               _Float16* __restrict__ WcT) {
    int kt = blockIdx.x;
    int nt = blockIdx.y;
    __shared__ _Float16 tile[32][33];
    int tx = threadIdx.x & 31, ty = threadIdx.x >> 5;
    int n0 = nt * 32, k0 = kt * 32;
    for (int r = 0; r < 32; r += 8) {
        int k = k0 + ty + r, n = n0 + tx;
        float v = (n < 512) ? W1[(size_t)k * 512 + n] : W2[(size_t)k * 512 + (n - 512)];
        tile[tx][ty + r] = (_Float16)v;
    }
    __syncthreads();
    for (int r = 0; r < 32; r += 8) {
        int n = n0 + ty + r, k = k0 + tx;
        WcT[(size_t)n * 512 + k] = tile[ty + r][tx];
    }
}

// ---------------- all f32 weight transposes in one kernel ----------------
__global__ __launch_bounds__(256) void transAll_k(const float* __restrict__ Lss, const float* __restrict__ Lgs,
                                                  const float* __restrict__ Lsy, const float* __restrict__ Lgy,
                                                  const float* __restrict__ Wsm, const float* __restrict__ Wsc,
                                                  const float* __restrict__ Lyy,
                                                  float* __restrict__ WgT, float* __restrict__ WyT,
                                                  float* __restrict__ WpT, float* __restrict__ LyyT) {
    int bid = blockIdx.x;
    const float* src; float* dst; int R, C, dstride, coloff, ctiles;
    if (bid < 256)       { src = Lss; dst = WgT;  R = 256; C = 1024; dstride = KV; coloff = 0;  ctiles = 32; }
    else if (bid < 768)  { src = Lgs; dst = WgT;  R = 512; C = 1024; dstride = KV; coloff = HN; ctiles = 32; bid -= 256; }
    else if (bid < 832)  { src = Lsy; dst = WyT;  R = 256; C = 256;  dstride = KV; coloff = 0;  ctiles = 8;  bid -= 768; }
    else if (bid < 960)  { src = Lgy; dst = WyT;  R = 512; C = 256;  dstride = KV; coloff = HN; ctiles = 8;  bid -= 832; }
    else if (bid < 1088) { src = Wsm; dst = WpT;  R = 256; C = 512;  dstride = HN; coloff = 0;  ctiles = 16; bid -= 960; }
    else if (bid < 1216) { src = Wsc; dst = WpT + (size_t)DN * HN; R = 256; C = 512; dstride = HN; coloff = 0; ctiles = 16; bid -= 1088; }
    else                 { src = Lyy; dst = LyyT; R = 256; C = 1000; dstride = HN; coloff = 0;  ctiles = 32; bid -= 1216; }
    int ct = bid % ctiles, rt = bid / ctiles;
    __shared__ float tile[32][33];
    int c0 = ct * 32, r0 = rt * 32;
    int tx = threadIdx.x & 31, ty = threadIdx.x >> 5;
    for (int rr = 0; rr < 32; rr += 8) {
        int r = r0 + ty + rr, cc = c0 + tx;
        tile[ty + rr][tx] = (r < R && cc < C) ? src[(size_t)r * C + cc] : 0.f;
    }
    __syncthreads();
    for (int rr = 0; rr < 32; rr += 8) {
        int cc = c0 + ty + rr, r = r0 + tx;
        if (cc < C && r < R) dst[(size_t)cc * dstride + coloff + r] = tile[tx][ty + rr];
    }
}

// ---------------- f16 MFMA GEMM: encMC[16384][1024] = A16 @ WcT^T ----------------
__global__ __launch_bounds__(256) void gemm16_k(const _Float16* __restrict__ A16,
                                                const _Float16* __restrict__ WcT,
                                                _Float16* __restrict__ encMC) {
    __shared__ _Float16 Alds[128 * 32];
    __shared__ _Float16 Blds[128 * 32];
    int bm = blockIdx.x;
    int bn = blockIdx.y;
    int tid = threadIdx.x;
    int lane = tid & 63;
    int w = tid >> 6;
    int wr = w >> 1, wc = w & 1;
    int lr = lane & 15;
    int kg = lane >> 4;
    f32x4 acc[4][4];
#pragma unroll
    for (int i = 0; i < 4; i++)
#pragma unroll
        for (int j = 0; j < 4; j++) acc[i][j] = (f32x4){0.f, 0.f, 0.f, 0.f};

    int wavebase = tid & ~63;
    for (int k0 = 0; k0 < 512; k0 += 32) {
        __syncthreads();
#pragma unroll
        for (int is = 0; is < 2; is++) {
            int l = is * 256 + tid;
            int row = l >> 2, kgs = l & 3;
            int kp = kgs ^ ((row ^ (row >> 2)) & 3);
            gload_lds16(A16 + (size_t)(bm * 128 + row) * 512 + k0 + kp * 8,
                        (char*)Alds + (size_t)(is * 256 + wavebase) * 16);
            gload_lds16(WcT + (size_t)(bn * 128 + row) * 512 + k0 + kp * 8,
                        (char*)Blds + (size_t)(is * 256 + wavebase) * 16);
        }
        __syncthreads();
        f16x8 af[4], bf[4];
#pragma unroll
        for (int mi = 0; mi < 4; mi++) {
            int r = wr * 64 + mi * 16 + lr;
            int kp = kg ^ ((r ^ (r >> 2)) & 3);
            af[mi] = *(const f16x8*)(Alds + r * 32 + kp * 8);
        }
#pragma unroll
        for (int ni = 0; ni < 4; ni++) {
            int cgl = wc * 64 + ni * 16 + lr;
            int kp = kg ^ ((cgl ^ (cgl >> 2)) & 3);
            bf[ni] = *(const f16x8*)(Blds + cgl * 32 + kp * 8);
        }
#pragma unroll
        for (int mi = 0; mi < 4; mi++)
#pragma unroll
            for (int ni = 0; ni < 4; ni++)
                acc[mi][ni] = __builtin_amdgcn_mfma_f32_16x16x32_f16(af[mi], bf[ni], acc[mi][ni], 0, 0, 0);
    }
    int cr = lane >> 4;
#pragma unroll
    for (int mi = 0; mi < 4; mi++)
#pragma unroll
        for (int ni = 0; ni < 4; ni++) {
            int col = bn * 128 + wc * 64 + ni * 16 + lr;
#pragma unroll
            for (int j = 0; j < 4; j++) {
                int row = bm * 128 + wr * 64 + mi * 16 + cr * 4 + j;
                encMC[(size_t)row * 1024 + col] = (_Float16)acc[mi][ni][j];
            }
        }
}

// ---------------- out projection as device fn (63 block-slots, 256 thr) ----------------
__device__ __forceinline__ void out_proj(int bid2, int tid, float* shbuf,
                                         const float* __restrict__ yv,
                                         const float* __restrict__ LyyT, const float* __restrict__ Lyyb,
                                         float* __restrict__ out, int tt) {
    for (int i = tid * 4; i < BB * HN; i += 1024)
        *(float4*)&shbuf[i] = *(const float4*)&yv[i];
    __syncthreads();
    int wave = tid >> 6, lane = tid & 63;
    int c0 = (bid2 * 4 + wave) * 4;
    for (int q = 0; q < 4; q++) {
        int cc = c0 + q;
        if (cc >= CCLS) break;
        const float* wp = LyyT + (size_t)cc * HN;
        float acc[BB] = {0.f};
#pragma unroll
        for (int k = 0; k < 4; k++) {
            int e = lane + k * 64;
            float wv = wp[e];
#pragma unroll
            for (int b = 0; b < BB; b++) acc[b] = fmaf(wv, shbuf[b * HN + e], acc[b]);
        }
#pragma unroll
        for (int b = 0; b < BB; b++)
#pragma unroll
            for (int off = 32; off > 0; off >>= 1) acc[b] += __shfl_xor(acc[b], off);
        if (lane == 0) {
            float bias = Lyyb[cc];
#pragma unroll
            for (int b = 0; b < BB; b++) out[((size_t)b * NSTEPS + tt) * CCLS + cc] = acc[b] + bias;
        }
    }
}

// ---------------- energies (blocks 0..4095) + out(t-1) (blocks 4096..4158) ----------------
__global__ __launch_bounds__(256) void energy_out_k(const _Float16* __restrict__ encMC,
                                                    const float* __restrict__ sm, const float* __restrict__ sc,
                                                    const float* __restrict__ vM, const float* __restrict__ vC,
                                                    const float* __restrict__ vnorm, const float* __restrict__ rmono,
                                                    const int* __restrict__ len, const float* __restrict__ noise_t,
                                                    float* __restrict__ p, float* __restrict__ ech,
                                                    const float* __restrict__ yv,
                                                    const float* __restrict__ LyyT, const float* __restrict__ Lyyb,
                                                    float* __restrict__ out, int t) {
    __shared__ float shbuf[BB * HN];
    int tid = threadIdx.x;
    if (blockIdx.x >= 4096) {
        if (t > 0) out_proj(blockIdx.x - 4096, tid, shbuf, yv, LyyT, Lyyb, out, t - 1);
        return;
    }
    int wave = blockIdx.x * 4 + (tid >> 6);
    int lane = tid & 63;
    int b = wave >> 10;
    int si = wave & 1023;
    const f16x8* row = (const f16x8*)(encMC + (size_t)wave * 1024);
    f16x8 em = row[lane];
    f16x8 ec = row[64 + lane];
    int d0 = lane * 8;
    float4 sma = *(const float4*)&sm[b * DN + d0];
    float4 smbv = *(const float4*)&sm[b * DN + d0 + 4];
    float4 sca = *(const float4*)&sc[b * DN + d0];
    float4 scbv = *(const float4*)&sc[b * DN + d0 + 4];
    float4 vma = *(const float4*)&vM[d0];
    float4 vmb = *(const float4*)&vM[d0 + 4];
    float4 vca = *(const float4*)&vC[d0];
    float4 vcb = *(const float4*)&vC[d0 + 4];
    float smv[8] = {sma.x, sma.y, sma.z, sma.w, smbv.x, smbv.y, smbv.z, smbv.w};
    float scv[8] = {sca.x, sca.y, sca.z, sca.w, scbv.x, scbv.y, scbv.z, scbv.w};
    float vmv[8] = {vma.x, vma.y, vma.z, vma.w, vmb.x, vmb.y, vmb.z, vmb.w};
    float vcv[8] = {vca.x, vca.y, vca.z, vca.w, vcb.x, vcb.y, vcb.z, vcb.w};
    float s1 = 0.f, s2 = 0.f;
#pragma unroll
    for (int j = 0; j < 8; j++) {
        s1 += ftanh((float)em[j] + smv[j]) * vmv[j];
        s2 += ftanh((float)ec[j] + scv[j]) * vcv[j];
    }
#pragma unroll
    for (int off = 32; off > 0; off >>= 1) {
        s1 += __shfl_xor(s1, off);
        s2 += __shfl_xor(s2, off);
    }
    if (lane == 0) {
        bool masked = (si >= len[b]);
        float pe;
        if (masked) {
            pe = 0.f;
        } else {
            float e = vnorm[0] * s1 + rmono[0] + noise_t[b * SS + si];
            pe = fsigm(e);
        }
        p[b * SS + si] = pe;
        ech[b * SS + si] = masked ? -INFINITY : s2;
    }
}

// ---------------- per-row scan: alpha recurrence + chunk softmax + beta ----------------
__global__ __launch_bounds__(1024) void scanrow_k(const float* __restrict__ p,
                                                  const float* __restrict__ aprev,
                                                  const float* __restrict__ ech,
                                                  float* __restrict__ anew,
                                                  float* __restrict__ beta) {
    int b = blockIdx.x;
    int i = threadIdx.x;
    int lane = i & 63, w = i >> 6;
    __shared__ float wred[16];
    __shared__ float wred2[16];
    __shared__ float mred[16];
    __shared__ float exS[SS];
    __shared__ float rS[SS];
    float pi = p[b * SS + i];
    float lf = (i < SS - 1) ? logf(fminf(fmaxf(1.f - pi, 1e-8f), 1.f)) : 0.f;
    float x = lf;
#pragma unroll
    for (int off = 1; off < 64; off <<= 1) {
        float n = __shfl_up(x, off);
        if (lane >= off) x += n;
    }
    if (lane == 63) wred[w] = x;
    float e = ech[b * SS + i];
    float mx = e;
#pragma unroll
    for (int off = 32; off > 0; off >>= 1) mx = fmaxf(mx, __shfl_xor(mx, off));
    if (lane == 0) mred[w] = mx;
    __syncthreads();
    float base = 0.f;
    for (int j = 0; j < 16; j++)
        if (j < w) base += wred[j];
    float csum = base + x;
    float cpp = expf(csum - lf);
    float u = aprev[b * SS + i] / fminf(fmaxf(cpp, 1e-8f), 1.f);
    float m = mred[0];
    for (int j = 1; j < 16; j++) m = fmaxf(m, mred[j]);
    float x2 = u;
#pragma unroll
    for (int off = 1; off < 64; off <<= 1) {
        float n = __shfl_up(x2, off);
        if (lane >= off) x2 += n;
    }
    if (lane == 63) wred2[w] = x2;
    __syncthreads();
    float base2 = 0.f;
    for (int j = 0; j < 16; j++)
        if (j < w) base2 += wred2[j];
    float q = cpp * (base2 + x2);
    float alpha = fminf(fmaxf(pi * q, 1e-8f), 1.f);
    anew[b * SS + i] = alpha;
    float ex = fmaxf(expf(e - m), 1e-5f);
    exS[i] = ex;
    __syncthreads();
    float denom = ex;
    if (i >= 1) denom += exS[i - 1];
    if (i >= 2) denom += exS[i - 2];
    if (i >= 3) denom += exS[i - 3];
    denom = fmaxf(denom, 1e-10f);
    rS[i] = alpha / denom;
    __syncthreads();
    float bsum = rS[i];
    if (i + 1 < SS) bsum += rS[i + 1];
    if (i + 2 < SS) bsum += rS[i + 2];
    if (i + 3 < SS) bsum += rS[i + 3];
    beta[b * SS + i] = ex * bsum;
}

// ---------------- ctx partials: grid (16,4), 512 thr; 4 chunks of 256 s ----------------
__global__ __launch_bounds__(512) void ctxpart_k(const float* __restrict__ beta,
                                                 const _Float16* __restrict__ enc16,
                                                 float* __restrict__ part4) {
    int b = blockIdx.x, chunk = blockIdx.y;
    int d = threadIdx.x;
    int s0 = chunk * 256;
    float acc0 = 0.f, acc1 = 0.f;
    const _Float16* eb = enc16 + ((size_t)(b * SS + s0)) * DN + d;
    const float* bb_ = beta + b * SS + s0;
#pragma unroll 4
    for (int s = 0; s < 256; s += 2) {
        acc0 = fmaf(bb_[s], (float)eb[(size_t)s * DN], acc0);
        acc1 = fmaf(bb_[s + 1], (float)eb[(size_t)(s + 1) * DN], acc1);
    }
    part4[((size_t)b * 4 + chunk) * DN + d] = acc0 + acc1;
}

// ---------------- fused ctx-reduce + gates + LSTM ----------------
__global__ __launch_bounds__(256) void gl_k(const float* __restrict__ part4,
                                            const float* __restrict__ sIn,
                                            const float* __restrict__ WgT,
                                            const int* __restrict__ target, int t,
                                            const float* __restrict__ Lys, const float* __restrict__ Lgsb,
                                            float* __restrict__ c, float* __restrict__ sOut) {
    __shared__ float sl[BB * KV];
    __shared__ float recL[2][4][BB];
    int tid = threadIdx.x;
    for (int i = tid; i < BB * HN; i += 256) {
        int b = i >> 8, d = i & (HN - 1);
        sl[b * KV + d] = sIn[b * KV + d];
    }
    for (int i = tid; i < BB * DN; i += 256) {
        int b = i >> 9, d = i & (DN - 1);
        const float* pp = part4 + ((size_t)b * 4) * DN + d;
        sl[b * KV + HN + d] = (pp[0] + pp[DN]) + (pp[2 * DN] + pp[3 * DN]);
    }
    __syncthreads();
    int wave = tid >> 6, lane = tid & 63;
    int h0 = blockIdx.x * 2;
    const float* w0p = WgT + (size_t)(h0 + wave * HN) * KV;
    const float* w1p = WgT + (size_t)(h0 + 1 + wave * HN) * KV;
    float acc0[BB] = {0.f}, acc1[BB] = {0.f};
#pragma unroll
    for (int j = 0; j < 12; j++) {
        int e = lane + j * 64;
        float w0 = w0p[e], w1 = w1p[e];
#pragma unroll
        for (int b = 0; b < BB; b++) {
            float xv = sl[b * KV + e];
            acc0[b] = fmaf(w0, xv, acc0[b]);
            acc1[b] = fmaf(w1, xv, acc1[b]);
        }
    }
#pragma unroll
    for (int b = 0; b < BB; b++)
#pragma unroll
        for (int off = 32; off > 0; off >>= 1) {
            acc0[b] += __shfl_xor(acc0[b], off);
            acc1[b] += __shfl_xor(acc1[b], off);
        }
    if (lane == 0) {
#pragma unroll
        for (int b = 0; b < BB; b++) {
            recL[0][wave][b] = acc0[b];
            recL[1][wave][b] = acc1[b];
        }
    }
    __syncthreads();
    if (tid < 32) {
        int b = tid & 15, hh = tid >> 4;
        int h = h0 + hh;
        int tgt = target[b * NSTEPS + t];
        const float* ys = Lys + (size_t)tgt * G4;
        float ri = recL[hh][0][b] + ys[h] + Lgsb[h];
        float rf = recL[hh][1][b] + ys[h + HN] + Lgsb[h + HN];
        float rg = recL[hh][2][b] + ys[h + 2 * HN] + Lgsb[h + 2 * HN];
        float ro = recL[hh][3][b] + ys[h + 3 * HN] + Lgsb[h + 3 * HN];
        float cn = fsigm(rf) * c[b * HN + h] + fsigm(ri) * ftanh(rg);
        float sn = fsigm(ro) * ftanh(cn);
        c[b * HN + h] = cn;
        sOut[b * KV + h] = sn;
    }
    if (blockIdx.x == 0) {
        for (int i = tid; i < BB * DN; i += 256) {
            int b = i >> 9, d = i & (DN - 1);
            sOut[b * KV + HN + d] = sl[b * KV + HN + d];
        }
    }
}

// ---------------- y gate (blocks 0..15) + next-step proj (blocks 16..79) ----------------
__global__ __launch_bounds__(256) void ypj_k(const float* __restrict__ sctx,
                                             const float* __restrict__ WyT, const float* __restrict__ Lgyb,
                                             const float* __restrict__ WpT,
                                             const float* __restrict__ Wsmb, const float* __restrict__ Wscb,
                                             float* __restrict__ yv,
                                             float* __restrict__ smb, float* __restrict__ scb) {
    __shared__ float sl[BB * KV];
    int tid = threadIdx.x;
    for (int i = tid * 4; i < BB * KV; i += 1024)
        *(float4*)&sl[i] = *(const float4*)&sctx[i];
    __syncthreads();
    int wave = tid >> 6, lane = tid & 63;
    if (blockIdx.x < 16) {
        int h0 = blockIdx.x * 16 + wave * 4;
        for (int q = 0; q < 4; q++) {
            int h = h0 + q;
            const float* wp = WyT + (size_t)h * KV;
            float acc[BB] = {0.f};
#pragma unroll
            for (int j = 0; j < 12; j++) {
                int e = lane + j * 64;
                float wv = wp[e];
#pragma unroll
                for (int b = 0; b < BB; b++) acc[b] = fmaf(wv, sl[b * KV + e], acc[b]);
            }
#pragma unroll
            for (int b = 0; b < BB; b++)
#pragma unroll
                for (int off = 32; off > 0; off >>= 1) acc[b] += __shfl_xor(acc[b], off);
            if (lane == 0) {
#pragma unroll
                for (int b = 0; b < BB; b++) yv[b * HN + h] = ftanh(acc[b] + Lgyb[h]);
            }
        }
    } else {
        int j0 = (blockIdx.x - 16) * 16 + wave * 4;
        for (int q = 0; q < 4; q++) {
            int jc = j0 + q;
            const float* wp = WpT + (size_t)jc * HN;
            float acc[BB] = {0.f};
#pragma unroll
            for (int k = 0; k < 4; k++) {
                int e = lane + k * 64;
                float wv = wp[e];
#pragma unroll
                for (int b = 0; b < BB; b++) acc[b] = fmaf(wv, sl[b * KV + e], acc[b]);
            }
#pragma unroll
            for (int b = 0; b < BB; b++)
#pragma unroll
                for (int off = 32; off > 0; off >>= 1) acc[b] += __shfl_xor(acc[b], off);
            if (lane == 0) {
                if (jc < DN) {
#pragma unroll
                    for (int b = 0; b < BB; b++) smb[b * DN + jc] = acc[b] + Wsmb[jc];
                } else {
                    int jj = jc - DN;
#pragma unroll
                    for (int b = 0; b < BB; b++) scb[b * DN + jj] = acc[b] + Wscb[jj];
                }
            }
        }
    }
}

// ---------------- standalone out projection (final step) ----------------
__global__ __launch_bounds__(256) void out_k(const float* __restrict__ yv,
                                             const float* __restrict__ LyyT, const float* __restrict__ Lyyb,
                                             float* __restrict__ out, int t) {
    __shared__ float shbuf[BB * HN];
    out_proj(blockIdx.x, threadIdx.x, shbuf, yv, LyyT, Lyyb, out, t);
}

extern "C" void kernel_launch(void* const* d_in, const int* in_sizes, int n_in,
                              void* d_out, int out_size, void* d_ws, size_t ws_size,
                              hipStream_t stream) {
    const float* enc  = (const float*)d_in[0];
    const int*   target = (const int*)d_in[1];
    const int*   len  = (const int*)d_in[2];
    const float* noise = (const float*)d_in[3];
    const float* Wsm  = (const float*)d_in[4];
    const float* Wsmb = (const float*)d_in[5];
    const float* WhM  = (const float*)d_in[6];
    const float* vM   = (const float*)d_in[7];
    const float* g    = (const float*)d_in[8];
    const float* rm   = (const float*)d_in[9];
    const float* Wsc  = (const float*)d_in[10];
    const float* Wscb = (const float*)d_in[11];
    const float* WhC  = (const float*)d_in[12];
    const float* vC   = (const float*)d_in[13];
    const float* Lsy  = (const float*)d_in[14];
    const float* Lgy  = (const float*)d_in[15];
    const float* Lgyb = (const float*)d_in[16];
    const float* Lyy  = (const float*)d_in[17];
    const float* Lyyb = (const float*)d_in[18];
    const float* Lys  = (const float*)d_in[19];
    const float* Lss  = (const float*)d_in[20];
    const float* Lgs  = (const float*)d_in[21];
    const float* Lgsb = (const float*)d_in[22];
    float* out = (float*)d_out;

    char* w = (char*)d_ws;
    size_t off = 0;
    auto alloc = [&](size_t bytes) { void* pp = w + off; off += (bytes + 255) & ~(size_t)255; return pp; };
    _Float16* A16   = (_Float16*)alloc((size_t)BB * SS * DN * 2);
    _Float16* WcT   = (_Float16*)alloc((size_t)1024 * 512 * 2);
    _Float16* encMC = (_Float16*)alloc((size_t)BB * SS * 1024 * 2);
    float* WgT  = (float*)alloc((size_t)G4 * KV * 4);
    float* WyT  = (float*)alloc((size_t)HN * KV * 4);
    float* WpT  = (float*)alloc((size_t)G4 * HN * 4);
    float* LyyT = (float*)alloc((size_t)CCLS * HN * 4);
    float* smb   = (float*)alloc(BB * DN * 4);
    float* scb   = (float*)alloc(BB * DN * 4);
    float* pbuf  = (float*)alloc(BB * SS * 4);
    float* ech   = (float*)alloc(BB * SS * 4);
    float* aA    = (float*)alloc(BB * SS * 4);
    float* aBf   = (float*)alloc(BB * SS * 4);
    float* betab = (float*)alloc(BB * SS * 4);
    float* part4 = (float*)alloc((size_t)BB * 4 * DN * 4);
    float* sctxA = (float*)alloc((size_t)BB * KV * 4);
    float* sctxB = (float*)alloc((size_t)BB * KV * 4);
    float* yvb   = (float*)alloc((size_t)BB * HN * 4);
    float* cbuf  = (float*)alloc(BB * HN * 4);
    float* vn    = (float*)alloc(16);
    (void)ws_size; (void)in_sizes; (void)n_in; (void)out_size;

    // ---- preamble (5 launches) ----
    init_k<<<97, 512, 0, stream>>>(vM, g, Wsmb, Wscb, aA, sctxA, cbuf, smb, scb, vn);
    conv_enc_k<<<4096, 256, 0, stream>>>(enc, A16);
    convW_k<<<dim3(16, 32), 256, 0, stream>>>(WhM, WhC, WcT);
    gemm16_k<<<dim3(128, 8), 256, 0, stream>>>(A16, WcT, encMC);
    transAll_k<<<1472, 256, 0, stream>>>(Lss, Lgs, Lsy, Lgy, Wsm, Wsc, Lyy, WgT, WyT, WpT, LyyT);

    for (int t = 0; t < NSTEPS; t++) {
        float* ain  = (t % 2 == 0) ? aA : aBf;
        float* aout = (t % 2 == 0) ? aBf : aA;
        float* sIn  = (t % 2 == 0) ? sctxA : sctxB;
        float* sOut = (t % 2 == 0) ? sctxB : sctxA;
        energy_out_k<<<4159, 256, 0, stream>>>(encMC, smb, scb, vM, vC, vn, rm,
                                               len, noise + (size_t)t * BB * SS, pbuf, ech,
                                               yvb, LyyT, Lyyb, out, t);
        scanrow_k<<<BB, 1024, 0, stream>>>(pbuf, ain, ech, aout, betab);
        ctxpart_k<<<dim3(BB, 4), 512, 0, stream>>>(betab, A16, part4);
        gl_k<<<128, 256, 0, stream>>>(part4, sIn, WgT, target, t, Lys, Lgsb, cbuf, sOut);
        ypj_k<<<80, 256, 0, stream>>>(sOut, WyT, Lgyb, WpT, Wsmb, Wscb, yvb, smb, scb);
    }
    out_k<<<63, 256, 0, stream>>>(yvb, LyyT, Lyyb, out, NSTEPS - 1);
}